// Round 4
// baseline (93.107 us; speedup 1.0000x reference)
//
#include <hip/hip_runtime.h>
#include <hip/hip_bf16.h>

// Problem constants: B=64, N=32, S=256, D=128
#define B_SZ 64

typedef __attribute__((ext_vector_type(8))) short bf16x8;
typedef __attribute__((ext_vector_type(4))) float f32x4;

static __device__ __forceinline__ unsigned short f2bf(float f) {
    __hip_bfloat16 h = __float2bfloat16(f);
    return *reinterpret_cast<unsigned short*>(&h);
}

// Load 8 consecutive fp32 (32 B), convert to one bf16x8 fragment.
static __device__ __forceinline__ bf16x8 cvt_frag(const float* __restrict__ src) {
    float4 a = reinterpret_cast<const float4*>(src)[0];
    float4 b = reinterpret_cast<const float4*>(src)[1];
    union { bf16x8 v; unsigned short u[8]; } t;
    t.u[0] = f2bf(a.x); t.u[1] = f2bf(a.y); t.u[2] = f2bf(a.z); t.u[3] = f2bf(a.w);
    t.u[4] = f2bf(b.x); t.u[5] = f2bf(b.y); t.u[6] = f2bf(b.z); t.u[7] = f2bf(b.w);
    return t.v;
}

#define MFMA(A, Bv, C) __builtin_amdgcn_mfma_f32_16x16x32_bf16(A, Bv, C, 0, 0, 0)

// fp32 -> bf16 convert + permute into MFMA fragment order.
// DP (ushort8 idx): doc*4096 + ch*1024 + kk*256 + nt*64 + lane
//    = doc[s = ch*64 + nt*16 + (lane&15)][k8 = kk*4 + (lane>>4)]   (doc 64..127 = nd)
// DP path: one block per (doc, ch). Reads coalesced (dense 32 KiB fp32 sub-tile),
// transpose through XOR-swizzled LDS (16 KiB), writes coalesced (dense 16 KiB).
// Swizzle a -> a ^ (((a>>8)&7)<<4) applied on BOTH LDS write and LDS read
// (same involution); read pattern spreads across all 32 banks, <=2-way.
// QP (ushort8 idx g): g = b*512 + kk*128 + mt*64 + ln (writes coalesced; reads
// are 32B granules at 512B stride on a 1 MiB input - negligible).
__global__ __launch_bounds__(256) void cvt_permute(const float* __restrict__ q,
                                                   const float* __restrict__ dd,
                                                   const float* __restrict__ nd,
                                                   unsigned short* __restrict__ DP,
                                                   unsigned short* __restrict__ QP) {
    const int blk = blockIdx.x, tid = threadIdx.x;
    if (blk < 512) {
        __shared__ bf16x8 lbuf[1024];            // 16 KiB bounce buffer
        const int doc = blk >> 2, ch = blk & 3;
        const float* src = ((doc < 64) ? (dd + (size_t)doc * 32768)
                                       : (nd + (size_t)(doc - 64) * 32768))
                           + ch * 8192;          // 64 rows x 128 floats
        char* lb = reinterpret_cast<char*>(lbuf);
        // dense read + convert + swizzled LDS write
        #pragma unroll
        for (int i = 0; i < 4; ++i) {
            const int rem = i * 256 + tid;       // octet index: s_local*16 + k8
            bf16x8 v = cvt_frag(src + rem * 8);
            const int a = (rem * 16) ^ (((rem >> 4) & 7) << 4);
            *reinterpret_cast<bf16x8*>(lb + a) = v;
        }
        __syncthreads();
        // swizzled LDS read + dense global write
        bf16x8* dst = reinterpret_cast<bf16x8*>(DP) + (size_t)doc * 4096 + ch * 1024;
        #pragma unroll
        for (int j = 0; j < 4; ++j) {
            const int u = j * 256 + tid;         // kk*256 + nt*64 + lane
            const int lane = u & 63, nt = (u >> 6) & 3, kk = u >> 8;
            const int s_local = nt * 16 + (lane & 15);
            const int k8 = kk * 4 + (lane >> 4);
            const int rem = s_local * 16 + k8;
            const int a = (rem * 16) ^ (((rem >> 4) & 7) << 4);
            dst[u] = *reinterpret_cast<const bf16x8*>(lb + a);
        }
    } else {
        const int g = (blk - 512) * 256 + tid;   // 0..32767
        const int b = g >> 9, u = g & 511;
        const int ln = u & 63, mt = (u >> 6) & 1, kk = u >> 7;
        const int n  = mt * 16 + (ln & 15);
        const int k0 = kk * 32 + (ln >> 4) * 8;
        reinterpret_cast<bf16x8*>(QP)[g] = cvt_frag(q + (size_t)b * 4096 + n * 128 + k0);
    }
}

// B-in-register MaxSim.
// wg < 512 (pos): x = wg&7 (XCD), i = wg>>3; column c = x*8 + (i&7) -> all 8
//   blocks of column c land on XCD x. Block covers b in [ (i>>3)*8, +8 ).
// wg >= 512 (neg): pair b = wg-512, doc slot 64+b, single-b loop.
// Wave w holds s-chunk w's 16 B-fragments in 64 VGPRs (staged ONCE, dense
// 1 KiB loads); inner loop over b reuses them: 8 A-frag loads + 32 MFMAs per b.
// No LDS doc tile; cross-chunk max via 4 KiB wred at the end.
__global__ __launch_bounds__(256, 2) void maxsim_kernel(const unsigned short* __restrict__ QP,
                                                        const unsigned short* __restrict__ DP,
                                                        float* __restrict__ scores) {
    const int wg  = blockIdx.x;
    const int tid = threadIdx.x;
    const int wave = tid >> 6, lane = tid & 63;
    const int l15 = lane & 15;

    __shared__ float wred[8][4][4][8];   // [bi][wave][lhi][mt*4+r]

    const bf16x8* DP8 = reinterpret_cast<const bf16x8*>(DP);
    const bf16x8* QP8 = reinterpret_cast<const bf16x8*>(QP);

    int c, b0, nb, dcc;
    if (wg < 512) {
        const int x = wg & 7, i = wg >> 3;
        c   = x * 8 + (i & 7);
        b0  = (i >> 3) * 8;
        nb  = 8;
        dcc = c;
    } else {
        b0 = wg - 512; c = 64; nb = 1; dcc = 64 + b0;
    }

    // ---- stage this wave's s-chunk (ch = wave) into registers: 16 dense loads ----
    bf16x8 Bv[4][4];                     // [kk][nt]
    const bf16x8* dsrc = DP8 + (size_t)dcc * 4096 + wave * 1024 + lane;
    #pragma unroll
    for (int kk = 0; kk < 4; ++kk)
        #pragma unroll
        for (int nt = 0; nt < 4; ++nt)
            Bv[kk][nt] = dsrc[kk * 256 + nt * 64];

    // ---- loop over batches: A-frags from QP (dense), 32 MFMAs, fold, stash ----
    #pragma unroll 2
    for (int bi = 0; bi < nb; ++bi) {
        const int b = b0 + bi;
        bf16x8 Af[4][2];
        const bf16x8* qsrc = QP8 + (size_t)b * 512 + lane;
        #pragma unroll
        for (int kk = 0; kk < 4; ++kk) {
            Af[kk][0] = qsrc[kk * 128];
            Af[kk][1] = qsrc[kk * 128 + 64];
        }
        f32x4 acc[2][4] = {};            // [mt][nt]
        #pragma unroll
        for (int kk = 0; kk < 4; ++kk)
            #pragma unroll
            for (int nt = 0; nt < 4; ++nt) {
                acc[0][nt] = MFMA(Af[kk][0], Bv[kk][nt], acc[0][nt]);
                acc[1][nt] = MFMA(Af[kk][1], Bv[kk][nt], acc[1][nt]);
            }
        // max over this wave's 64 docs; butterfly over l15 -> per-row chunk max
        #pragma unroll
        for (int mt = 0; mt < 2; ++mt)
            #pragma unroll
            for (int r = 0; r < 4; ++r) {
                float m = fmaxf(fmaxf(acc[mt][0][r], acc[mt][1][r]),
                                fmaxf(acc[mt][2][r], acc[mt][3][r]));
                m = fmaxf(m, __shfl_xor(m, 1, 64));
                m = fmaxf(m, __shfl_xor(m, 2, 64));
                m = fmaxf(m, __shfl_xor(m, 4, 64));
                m = fmaxf(m, __shfl_xor(m, 8, 64));
                if (l15 == 0) wred[bi][wave][lane >> 4][mt * 4 + r] = m;
                // row n = mt*16 + (lane>>4)*4 + r
            }
    }
    __syncthreads();

    // ---- final: max over the 4 s-chunks, then sum over the 32 query rows ----
    if (tid < nb * 32) {
        const int bi = tid >> 5, n = tid & 31;
        const int slot = (n >> 4) * 4 + (n & 3);   // mt*4 + r
        const int lhi  = (n >> 2) & 3;
        float m = fmaxf(fmaxf(wred[bi][0][lhi][slot], wred[bi][1][lhi][slot]),
                        fmaxf(wred[bi][2][lhi][slot], wred[bi][3][lhi][slot]));
        m += __shfl_xor(m, 1, 32);
        m += __shfl_xor(m, 2, 32);
        m += __shfl_xor(m, 4, 32);
        m += __shfl_xor(m, 8, 32);
        m += __shfl_xor(m, 16, 32);
        if (n == 0) scores[(size_t)(b0 + bi) * 65 + c] = m;  // c==64 -> neg slot
    }
}

static __device__ __forceinline__ float softplusf(float x) {
    return fmaxf(x, 0.0f) + log1pf(expf(-fabsf(x)));
}

__global__ __launch_bounds__(64) void loss_kernel(const float* __restrict__ scores,
                                                  float* __restrict__ out) {
    const int b = threadIdx.x;           // 64 threads = 1 wave
    const float* row = scores + b * 65;
    const float pos  = row[b];
    const float negq = row[64];
    float nib = -1e30f;
    #pragma unroll
    for (int c = 0; c < B_SZ; ++c) {
        float v = row[c] - ((c == b) ? 1000000.0f : 0.0f);
        nib = fmaxf(nib, v);
    }
    float t = softplusf(negq - pos) + softplusf(nib - pos);
    t += __shfl_xor(t, 1, 64);
    t += __shfl_xor(t, 2, 64);
    t += __shfl_xor(t, 4, 64);
    t += __shfl_xor(t, 8, 64);
    t += __shfl_xor(t, 16, 64);
    t += __shfl_xor(t, 32, 64);
    if (b == 0) out[0] = t * (0.5f / 64.0f);
}

extern "C" void kernel_launch(void* const* d_in, const int* in_sizes, int n_in,
                              void* d_out, int out_size, void* d_ws, size_t ws_size,
                              hipStream_t stream) {
    const float* q  = (const float*)d_in[0];   // (64, 32, 128)
    const float* dd = (const float*)d_in[1];   // (64, 256, 128)
    const float* nd = (const float*)d_in[2];   // (64, 256, 128)
    float* out = (float*)d_out;

    // Workspace: DP (128 x 4096 ushort8 = 8 MiB) | QP (64 x 512 ushort8 = 512 KiB)
    //            | scores (64 x 65 f32)
    unsigned short* DP = (unsigned short*)d_ws;
    unsigned short* QP = DP + (size_t)128 * 32768;
    float* scores = (float*)(QP + (size_t)64 * 4096);

    cvt_permute<<<640, 256, 0, stream>>>(q, dd, nd, DP, QP);
    maxsim_kernel<<<512 + B_SZ, 256, 0, stream>>>(QP, DP, scores);
    loss_kernel<<<1, 64, 0, stream>>>(scores, out);
}